// Round 12
// baseline (76.508 us; speedup 1.0000x reference)
//
#include <hip/hip_runtime.h>
#include <hip/hip_bf16.h>

// out[b,n] = 2*x.y - ||x_b||^2 - ||y_n||^2
// x: [M=4096, K=1024] f32   y: [N=8192, K=1024] f32   out: [M, N] f32
//
// Round 12: i8 MFMA at REAL multi-block occupancy. 128x128 tile, BK=64,
// 256 thr (4 waves, wave-tile 64x64), LDS 32 KiB, ~128 regs/wave ->
// __launch_bounds__(256,4) = 4 blocks/CU. Simple m97 2-barrier K-loop;
// cross-block TLP hides prologue/epilogue/barrier stalls that 1-block/CU
// rounds 2-11 left exposed. Swizzle re-derived for 64 B rows (2 lanes/bank).
// out = (2*sx[b])*sy[n]*dot_i32 - xsq[b] - ysq[n].

typedef __attribute__((ext_vector_type(4))) int i32x4;

#define KD 1024                // K elements (= bytes per i8 row)
#define NT 16                  // K-tiles of BK=64

__device__ __forceinline__ void gld16(const void* g, void* l) {
    __builtin_amdgcn_global_load_lds(
        (const __attribute__((address_space(1))) unsigned int*)g,
        (__attribute__((address_space(3))) unsigned int*)l,
        16, 0, 0);
}

// ------------- prep: per-row amax + sumsq + i8 quantize -------------------
__global__ __launch_bounds__(256) void prep_q(
    const float* __restrict__ x, const float* __restrict__ y,
    signed char* __restrict__ xq, signed char* __restrict__ yq,
    float* __restrict__ sx, float* __restrict__ sy,
    float* __restrict__ xsq, float* __restrict__ ysq, int M, int N)
{
    int row = blockIdx.x;
    const float* src;
    signed char* dst;
    float* nrm;
    float* scl;
    float sfac;
    if (row < M) {
        src = x + (size_t)row * KD; dst = xq + (size_t)row * KD;
        nrm = xsq + row; scl = sx + row; sfac = 2.0f;   // fold the 2* here
    } else {
        int r = row - M;
        src = y + (size_t)r * KD; dst = yq + (size_t)r * KD;
        nrm = ysq + r; scl = sy + r; sfac = 1.0f;
    }
    int t = threadIdx.x;                        // 256 threads, 4 floats each
    float4 v = ((const float4*)src)[t];
    float ss = v.x * v.x + v.y * v.y + v.z * v.z + v.w * v.w;
    float am = fmaxf(fmaxf(fabsf(v.x), fabsf(v.y)),
                     fmaxf(fabsf(v.z), fabsf(v.w)));
    #pragma unroll
    for (int off = 32; off > 0; off >>= 1) {
        ss += __shfl_down(ss, off, 64);
        am = fmaxf(am, __shfl_down(am, off, 64));
    }
    __shared__ float rs[4], rm[4];
    if ((t & 63) == 0) { rs[t >> 6] = ss; rm[t >> 6] = am; }
    __syncthreads();
    float tots = rs[0] + rs[1] + rs[2] + rs[3];
    float totm = fmaxf(fmaxf(rm[0], rm[1]), fmaxf(rm[2], rm[3]));
    float inv = totm > 0.0f ? 127.0f / totm : 0.0f;

    int q0 = (int)rintf(v.x * inv), q1 = (int)rintf(v.y * inv);
    int q2 = (int)rintf(v.z * inv), q3 = (int)rintf(v.w * inv);
    q0 = max(-127, min(127, q0)); q1 = max(-127, min(127, q1));
    q2 = max(-127, min(127, q2)); q3 = max(-127, min(127, q3));
    int packed = (q0 & 255) | ((q1 & 255) << 8) |
                 ((q2 & 255) << 16) | ((q3 & 255) << 24);
    ((int*)dst)[t] = packed;
    if (t == 0) { *nrm = tots; *scl = sfac * totm / 127.0f; }
}

// ------------- main 128x128 4-wave i8 MFMA GEMM (4 blocks/CU) -------------
// LDS bytes: A[2buf][128 rows][64 B] = 0..16383, B same 16384..32767.
__global__ __launch_bounds__(256, 4) void gemm_i8(
    const signed char* __restrict__ xq, const signed char* __restrict__ yq,
    const float* __restrict__ sx, const float* __restrict__ sy,
    const float* __restrict__ xsq, const float* __restrict__ ysq,
    float* __restrict__ out, int M, int N)
{
    __shared__ __align__(16) char lds[32768];   // 32 KiB

    const int ntm = M / 128;            // 32
    const int ntn = N / 128;            // 64
    const int bid = blockIdx.x;
    int tm, tn;
    if (ntm == 32 && ntn == 64) {
        // XCD-region swizzle: each XCD owns an 8(tm) x 32(tn) region.
        int xcd = bid & 7, k = bid >> 3;            // k = 0..255
        tm = (xcd >> 1) * 8 + (k >> 5);
        tn = (xcd & 1) * 32 + (k & 31);
    } else {
        tm = bid / ntn;
        tn = bid % ntn;
    }

    const int tid  = threadIdx.x;       // 256 threads = 4 waves (2x2)
    const int wid  = tid >> 6;
    const int lane = tid & 63;
    const int wr   = wid >> 1;          // 0..1  (wave tile: 64 x 64)
    const int wc   = wid & 1;           // 0..1
    const int l15  = lane & 15;
    const int hi   = lane >> 4;         // 0..3

    // ---- staging: dest LINEAR (tid*16B within 64-row chunk); global
    // source 16B-block pre-permuted: cbs = (tid&3) ^ (row&3), row = tid>>2.
    // 256 thr x 16 B = 4 KB = 64 rows of 64 B; 128-row tile = 2 chunks.
    const int srow = tid >> 2;          // 0..63
    const int cbs  = (tid & 3) ^ (srow & 3);
    const signed char* aBase = xq + (size_t)(tm * 128 + srow) * KD + cbs * 16;
    const signed char* bBase = yq + (size_t)(tn * 128 + srow) * KD + cbs * 16;
    const int dstB = tid * 16;

    #define STAGE(kt, buf) do {                                               \
        const signed char* ga_ = aBase + (size_t)(kt) * 64;                   \
        const signed char* gb_ = bBase + (size_t)(kt) * 64;                   \
        char* da_ = &lds[(buf) * 8192 + dstB];                                \
        char* db_ = &lds[16384 + (buf) * 8192 + dstB];                        \
        gld16(ga_, da_); gld16(ga_ + 64 * KD, da_ + 4096);                    \
        gld16(gb_, db_); gld16(gb_ + 64 * KD, db_ + 4096);                    \
    } while (0)

    // ---- fragment read offsets (bytes); phys 16B-block = hi ^ (l15&3) ----
    // bank check: lanes 0..15 (rows 0..15, same hi): bank = 16*(row&1)
    //   + 4*((hi^(row&3))&3) -> 8 distinct banks x 2 lanes = conflict-free.
    int aro[4], bro[4];
    #pragma unroll
    for (int mi = 0; mi < 4; ++mi) aro[mi] = (wr * 64 + mi * 16 + l15) * 64;
    #pragma unroll
    for (int nj = 0; nj < 4; ++nj) bro[nj] = (wc * 64 + nj * 16 + l15) * 64;
    const int xk = (hi ^ (l15 & 3)) * 16;

    i32x4 acc[4][4] = {};               // 64 regs

    // ---- prologue ----
    STAGE(0, 0);
    __syncthreads();

    int buf = 0;
    for (int t = 0; t < NT; ++t) {
        if (t + 1 < NT) STAGE(t + 1, buf ^ 1);
        const int ab = buf * 8192;

        i32x4 aF[4], bF[4];
        #pragma unroll
        for (int mi = 0; mi < 4; ++mi)
            aF[mi] = *(const i32x4*)&lds[ab + aro[mi] + xk];
        #pragma unroll
        for (int nj = 0; nj < 4; ++nj)
            bF[nj] = *(const i32x4*)&lds[16384 + ab + bro[nj] + xk];
        __builtin_amdgcn_s_setprio(1);
        #pragma unroll
        for (int mi = 0; mi < 4; ++mi)
            #pragma unroll
            for (int nj = 0; nj < 4; ++nj)
                acc[mi][nj] = __builtin_amdgcn_mfma_i32_16x16x64_i8(
                    aF[mi], bF[nj], acc[mi][nj], 0, 0, 0);
        __builtin_amdgcn_s_setprio(0);
        __syncthreads();    // drains stage (vmcnt0) + read-WAR for next tile
        buf ^= 1;
    }

    // ---- epilogue: out = sx2[row]*sy[col]*dot - xsq[row] - ysq[col] ----
    // C/D layout (16x16): col = lane&15, row = (lane>>4)*4 + reg
    #pragma unroll
    for (int mi = 0; mi < 4; ++mi) {
        int r0 = tm * 128 + wr * 64 + mi * 16 + hi * 4;
        #pragma unroll
        for (int nj = 0; nj < 4; ++nj) {
            int c = tn * 128 + wc * 64 + nj * 16 + l15;
            float syv = sy[c];
            float ysv = ysq[c];
            #pragma unroll
            for (int r = 0; r < 4; ++r) {
                int row = r0 + r;
                out[(size_t)row * N + c] =
                    sx[row] * syv * (float)acc[mi][nj][r] - xsq[row] - ysv;
            }
        }
    }
}

// ---------------- fallback (shape/ws mismatch): exact f32 -----------------
__global__ __launch_bounds__(256) void fallback_l2(
    const float* __restrict__ x, const float* __restrict__ y,
    float* __restrict__ out, int M, int N, int K)
{
    int tx = threadIdx.x & 15, ty = threadIdx.x >> 4;
    int row = blockIdx.y * 16 + ty;
    int col = blockIdx.x * 16 + tx;
    __shared__ float xs[16][17], ys[16][17];
    float s = 0.f;
    for (int k0 = 0; k0 < K; k0 += 16) {
        xs[ty][tx] = x[(size_t)row * K + k0 + tx];
        ys[ty][tx] = y[(size_t)(blockIdx.x * 16 + ty) * K + k0 + tx];
        __syncthreads();
        #pragma unroll
        for (int kk = 0; kk < 16; ++kk) {
            float d = xs[ty][kk] - ys[tx][kk];
            s += d * d;
        }
        __syncthreads();
    }
    out[(size_t)row * N + col] = -s;
}

extern "C" void kernel_launch(void* const* d_in, const int* in_sizes, int n_in,
                              void* d_out, int out_size, void* d_ws, size_t ws_size,
                              hipStream_t stream) {
    const float* x = (const float*)d_in[0];
    const float* y = (const float*)d_in[1];
    float* out = (float*)d_out;
    const int M = in_sizes[0] / KD;   // 4096
    const int N = in_sizes[1] / KD;   // 8192

    size_t need = (size_t)(M + N) * KD            // i8 matrices
                + (size_t)(M + N) * 2 * sizeof(float) + 256;
    if (ws_size >= need && M == 4096 && N == 8192) {
        char* w = (char*)d_ws;
        signed char* xq = (signed char*)w;
        signed char* yq = xq + (size_t)M * KD;
        float* sx  = (float*)(yq + (size_t)N * KD);
        float* sy  = sx + M;
        float* xsq = sy + N;
        float* ysq = xsq + M;

        prep_q<<<M + N, 256, 0, stream>>>(x, y, xq, yq, sx, sy, xsq, ysq, M, N);
        int grid = (M / 128) * (N / 128);   // 2048
        gemm_i8<<<grid, 256, 0, stream>>>(xq, yq, sx, sy, xsq, ysq, out, M, N);
    } else {
        dim3 g(N / 16, M / 16);
        fallback_l2<<<g, 256, 0, stream>>>(x, y, out, M, N, KD);
    }
}

// Round 13
// 69.072 us; speedup vs baseline: 1.1077x; 1.1077x over previous
//
#include <hip/hip_runtime.h>
#include <hip/hip_bf16.h>

// out[b,n] = 2*x.y - ||x_b||^2 - ||y_n||^2
// x: [M=4096, K=1024] f32   y: [N=8192, K=1024] f32   out: [M, N] f32
//
// Round 13: i8 MFMA, 128x256 tile @ 2 blocks/CU (the only geometry where
// multi-block occupancy fits the VGPR file: acc 128 KB/block x2 = half file).
// BK=64, 512 thr (8 waves 2x4, wave-tile 64x64, acc 64 regs), LDS 48 KB.
// m97-style 1-sync-per-K-tile loop; cross-BLOCK TLP hides barrier/epilogue
// stalls. Round-12 verified 64B-row swizzle (conflict-free), XCD 8x16 region.
// out = (2*sx[b])*sy[n]*dot_i32 - xsq[b] - ysq[n].

typedef __attribute__((ext_vector_type(4))) int i32x4;

#define KD 1024                // K elements (= bytes per i8 row)
#define NT 16                  // K-tiles of BK=64

__device__ __forceinline__ void gld16(const void* g, void* l) {
    __builtin_amdgcn_global_load_lds(
        (const __attribute__((address_space(1))) unsigned int*)g,
        (__attribute__((address_space(3))) unsigned int*)l,
        16, 0, 0);
}

// ------------- prep: per-row amax + sumsq + i8 quantize -------------------
__global__ __launch_bounds__(256) void prep_q(
    const float* __restrict__ x, const float* __restrict__ y,
    signed char* __restrict__ xq, signed char* __restrict__ yq,
    float* __restrict__ sx, float* __restrict__ sy,
    float* __restrict__ xsq, float* __restrict__ ysq, int M, int N)
{
    int row = blockIdx.x;
    const float* src;
    signed char* dst;
    float* nrm;
    float* scl;
    float sfac;
    if (row < M) {
        src = x + (size_t)row * KD; dst = xq + (size_t)row * KD;
        nrm = xsq + row; scl = sx + row; sfac = 2.0f;   // fold the 2* here
    } else {
        int r = row - M;
        src = y + (size_t)r * KD; dst = yq + (size_t)r * KD;
        nrm = ysq + r; scl = sy + r; sfac = 1.0f;
    }
    int t = threadIdx.x;                        // 256 threads, 4 floats each
    float4 v = ((const float4*)src)[t];
    float ss = v.x * v.x + v.y * v.y + v.z * v.z + v.w * v.w;
    float am = fmaxf(fmaxf(fabsf(v.x), fabsf(v.y)),
                     fmaxf(fabsf(v.z), fabsf(v.w)));
    #pragma unroll
    for (int off = 32; off > 0; off >>= 1) {
        ss += __shfl_down(ss, off, 64);
        am = fmaxf(am, __shfl_down(am, off, 64));
    }
    __shared__ float rs[4], rm[4];
    if ((t & 63) == 0) { rs[t >> 6] = ss; rm[t >> 6] = am; }
    __syncthreads();
    float tots = rs[0] + rs[1] + rs[2] + rs[3];
    float totm = fmaxf(fmaxf(rm[0], rm[1]), fmaxf(rm[2], rm[3]));
    float inv = totm > 0.0f ? 127.0f / totm : 0.0f;

    int q0 = (int)rintf(v.x * inv), q1 = (int)rintf(v.y * inv);
    int q2 = (int)rintf(v.z * inv), q3 = (int)rintf(v.w * inv);
    q0 = max(-127, min(127, q0)); q1 = max(-127, min(127, q1));
    q2 = max(-127, min(127, q2)); q3 = max(-127, min(127, q3));
    int packed = (q0 & 255) | ((q1 & 255) << 8) |
                 ((q2 & 255) << 16) | ((q3 & 255) << 24);
    ((int*)dst)[t] = packed;
    if (t == 0) { *nrm = tots; *scl = sfac * totm / 127.0f; }
}

// ------------- main 128x256 8-wave i8 MFMA GEMM (2 blocks/CU) -------------
// LDS bytes per buffer (24576): A[128 rows][64 B] = 0..8191,
//                               B[256 rows][64 B] = 8192..24575.
__global__ __launch_bounds__(512, 4) void gemm_i8(
    const signed char* __restrict__ xq, const signed char* __restrict__ yq,
    const float* __restrict__ sx, const float* __restrict__ sy,
    const float* __restrict__ xsq, const float* __restrict__ ysq,
    float* __restrict__ out, int M, int N)
{
    __shared__ __align__(16) char lds[49152];   // 48 KiB

    const int ntm = M / 128;            // 32
    const int ntn = N / 256;            // 32
    const int bid = blockIdx.x;
    int tm, tn;
    if (ntm == 32 && ntn == 32) {
        // XCD-region swizzle: each XCD owns an 8(tm) x 16(tn) region.
        int xcd = bid & 7, k = bid >> 3;            // k = 0..127
        tm = (xcd >> 1) * 8 + (k >> 4);
        tn = (xcd & 1) * 16 + (k & 15);
    } else {
        tm = bid / ntn;
        tn = bid % ntn;
    }

    const int tid  = threadIdx.x;       // 512 threads = 8 waves (2x4)
    const int wid  = tid >> 6;
    const int lane = tid & 63;
    const int wr   = wid >> 2;          // 0..1  (wave tile: 64 x 64)
    const int wc   = wid & 3;           // 0..3
    const int l15  = lane & 15;
    const int hi   = lane >> 4;         // 0..3

    // ---- staging: dest LINEAR (tid*16B); global source 16B-block
    // pre-permuted: cbs = (tid&3) ^ (row&3), row = tid>>2 (0..127).
    // A tile (128x64B = 8KB) = 1 issue; B tile (256x64B = 16KB) = 2 issues.
    const int srow = tid >> 2;          // 0..127
    const int cbs  = (tid & 3) ^ (srow & 3);
    const signed char* aBase = xq + (size_t)(tm * 128 + srow) * KD + cbs * 16;
    const signed char* bBase = yq + (size_t)(tn * 256 + srow) * KD + cbs * 16;
    const int dstB = tid * 16;

    #define STAGE(kt, buf) do {                                               \
        const signed char* ga_ = aBase + (size_t)(kt) * 64;                   \
        const signed char* gb_ = bBase + (size_t)(kt) * 64;                   \
        char* da_ = &lds[(buf) * 24576 + dstB];                               \
        char* db_ = &lds[(buf) * 24576 + 8192 + dstB];                        \
        gld16(ga_, da_);                                                      \
        gld16(gb_, db_); gld16(gb_ + 128 * KD, db_ + 8192);                   \
    } while (0)

    // ---- fragment read offsets (bytes); phys 16B-block = hi ^ (l15&3) ----
    // lanes 0..15 (same hi): bank = 16*(row&1)/4 + 4*((hi^(row&3))&3)
    //   -> 8 distinct banks x 2 lanes = conflict-free (2-way is free).
    int aro[4], bro[4];
    #pragma unroll
    for (int mi = 0; mi < 4; ++mi) aro[mi] = (wr * 64 + mi * 16 + l15) * 64;
    #pragma unroll
    for (int nj = 0; nj < 4; ++nj) bro[nj] = 8192 + (wc * 64 + nj * 16 + l15) * 64;
    const int xk = (hi ^ (l15 & 3)) * 16;

    i32x4 acc[4][4] = {};               // 64 regs

    // ---- prologue ----
    STAGE(0, 0);
    __syncthreads();

    int buf = 0;
    for (int t = 0; t < NT; ++t) {
        if (t + 1 < NT) STAGE(t + 1, buf ^ 1);
        const int ab = buf * 24576;

        i32x4 aF[4], bF[4];
        #pragma unroll
        for (int mi = 0; mi < 4; ++mi)
            aF[mi] = *(const i32x4*)&lds[ab + aro[mi] + xk];
        #pragma unroll
        for (int nj = 0; nj < 4; ++nj)
            bF[nj] = *(const i32x4*)&lds[ab + bro[nj] + xk];
        __builtin_amdgcn_s_setprio(1);
        #pragma unroll
        for (int mi = 0; mi < 4; ++mi)
            #pragma unroll
            for (int nj = 0; nj < 4; ++nj)
                acc[mi][nj] = __builtin_amdgcn_mfma_i32_16x16x64_i8(
                    aF[mi], bF[nj], acc[mi][nj], 0, 0, 0);
        __builtin_amdgcn_s_setprio(0);
        __syncthreads();    // drains stage (vmcnt0) + read-WAR for next tile
        buf ^= 1;
    }

    // ---- epilogue: out = sx2[row]*sy[col]*dot - xsq[row] - ysq[col] ----
    // C/D layout (16x16): col = lane&15, row = (lane>>4)*4 + reg
    #pragma unroll
    for (int mi = 0; mi < 4; ++mi) {
        int r0 = tm * 128 + wr * 64 + mi * 16 + hi * 4;
        #pragma unroll
        for (int nj = 0; nj < 4; ++nj) {
            int c = tn * 256 + wc * 64 + nj * 16 + l15;
            float syv = sy[c];
            float ysv = ysq[c];
            #pragma unroll
            for (int r = 0; r < 4; ++r) {
                int row = r0 + r;
                out[(size_t)row * N + c] =
                    sx[row] * syv * (float)acc[mi][nj][r] - xsq[row] - ysv;
            }
        }
    }
}

// ---------------- fallback (shape/ws mismatch): exact f32 -----------------
__global__ __launch_bounds__(256) void fallback_l2(
    const float* __restrict__ x, const float* __restrict__ y,
    float* __restrict__ out, int M, int N, int K)
{
    int tx = threadIdx.x & 15, ty = threadIdx.x >> 4;
    int row = blockIdx.y * 16 + ty;
    int col = blockIdx.x * 16 + tx;
    __shared__ float xs[16][17], ys[16][17];
    float s = 0.f;
    for (int k0 = 0; k0 < K; k0 += 16) {
        xs[ty][tx] = x[(size_t)row * K + k0 + tx];
        ys[ty][tx] = y[(size_t)(blockIdx.x * 16 + ty) * K + k0 + tx];
        __syncthreads();
        #pragma unroll
        for (int kk = 0; kk < 16; ++kk) {
            float d = xs[ty][kk] - ys[tx][kk];
            s += d * d;
        }
        __syncthreads();
    }
    out[(size_t)row * N + col] = -s;
}

extern "C" void kernel_launch(void* const* d_in, const int* in_sizes, int n_in,
                              void* d_out, int out_size, void* d_ws, size_t ws_size,
                              hipStream_t stream) {
    const float* x = (const float*)d_in[0];
    const float* y = (const float*)d_in[1];
    float* out = (float*)d_out;
    const int M = in_sizes[0] / KD;   // 4096
    const int N = in_sizes[1] / KD;   // 8192

    size_t need = (size_t)(M + N) * KD            // i8 matrices
                + (size_t)(M + N) * 2 * sizeof(float) + 256;
    if (ws_size >= need && M == 4096 && N == 8192) {
        char* w = (char*)d_ws;
        signed char* xq = (signed char*)w;
        signed char* yq = xq + (size_t)M * KD;
        float* sx  = (float*)(yq + (size_t)N * KD);
        float* sy  = sx + M;
        float* xsq = sy + N;
        float* ysq = xsq + M;

        prep_q<<<M + N, 256, 0, stream>>>(x, y, xq, yq, sx, sy, xsq, ysq, M, N);
        int grid = (M / 128) * (N / 256);   // 1024
        gemm_i8<<<grid, 512, 0, stream>>>(xq, yq, sx, sy, xsq, ysq, out, M, N);
    } else {
        dim3 g(N / 16, M / 16);
        fallback_l2<<<g, 256, 0, stream>>>(x, y, out, M, N, KD);
    }
}

// Round 14
// 63.872 us; speedup vs baseline: 1.1978x; 1.0814x over previous
//
#include <hip/hip_runtime.h>
#include <hip/hip_bf16.h>

// out[b,n] = 2*x.y - ||x_b||^2 - ||y_n||^2
// x: [M=4096, K=1024] f32   y: [N=8192, K=1024] f32   out: [M, N] f32
//
// Round 14: i8 MFMA 256x256 (round-10 geometry) with DOUBLE-BUFFERED
// FRAGMENT REGISTERS: MFMA never waits on lgkm (consumes prev-step regs);
// 12 ds_reads/step fill the alternate set. 16 steps = 8 K-tiles x 2 k-halves,
// ONE barrier per tile (8 total vs round-10's 32). vmcnt(0)+BAR mid-tile
// guarantees cross-wave stage visibility before the other set's reads.
// T2 swizzle (conflicts=0), XCD 8x8 region, setprio. ~185 VGPR (fits 2 w/SIMD).

typedef __attribute__((ext_vector_type(4))) int i32x4;

#define BM 256
#define BN 256
#define KD 1024                // K elements (= bytes per i8 row)
#define NT 8                   // K-tiles of BK=128

__device__ __forceinline__ void gld16(const void* g, void* l) {
    __builtin_amdgcn_global_load_lds(
        (const __attribute__((address_space(1))) unsigned int*)g,
        (__attribute__((address_space(3))) unsigned int*)l,
        16, 0, 0);
}

#define BAR() asm volatile("s_barrier" ::: "memory")

// ------------- prep: per-row amax + sumsq + i8 quantize -------------------
__global__ __launch_bounds__(256) void prep_q(
    const float* __restrict__ x, const float* __restrict__ y,
    signed char* __restrict__ xq, signed char* __restrict__ yq,
    float* __restrict__ sx, float* __restrict__ sy,
    float* __restrict__ xsq, float* __restrict__ ysq, int M, int N)
{
    int row = blockIdx.x;
    const float* src;
    signed char* dst;
    float* nrm;
    float* scl;
    float sfac;
    if (row < M) {
        src = x + (size_t)row * KD; dst = xq + (size_t)row * KD;
        nrm = xsq + row; scl = sx + row; sfac = 2.0f;   // fold the 2* here
    } else {
        int r = row - M;
        src = y + (size_t)r * KD; dst = yq + (size_t)r * KD;
        nrm = ysq + r; scl = sy + r; sfac = 1.0f;
    }
    int t = threadIdx.x;                        // 256 threads, 4 floats each
    float4 v = ((const float4*)src)[t];
    float ss = v.x * v.x + v.y * v.y + v.z * v.z + v.w * v.w;
    float am = fmaxf(fmaxf(fabsf(v.x), fabsf(v.y)),
                     fmaxf(fabsf(v.z), fabsf(v.w)));
    #pragma unroll
    for (int off = 32; off > 0; off >>= 1) {
        ss += __shfl_down(ss, off, 64);
        am = fmaxf(am, __shfl_down(am, off, 64));
    }
    __shared__ float rs[4], rm[4];
    if ((t & 63) == 0) { rs[t >> 6] = ss; rm[t >> 6] = am; }
    __syncthreads();
    float tots = rs[0] + rs[1] + rs[2] + rs[3];
    float totm = fmaxf(fmaxf(rm[0], rm[1]), fmaxf(rm[2], rm[3]));
    float inv = totm > 0.0f ? 127.0f / totm : 0.0f;

    int q0 = (int)rintf(v.x * inv), q1 = (int)rintf(v.y * inv);
    int q2 = (int)rintf(v.z * inv), q3 = (int)rintf(v.w * inv);
    q0 = max(-127, min(127, q0)); q1 = max(-127, min(127, q1));
    q2 = max(-127, min(127, q2)); q3 = max(-127, min(127, q3));
    int packed = (q0 & 255) | ((q1 & 255) << 8) |
                 ((q2 & 255) << 16) | ((q3 & 255) << 24);
    ((int*)dst)[t] = packed;
    if (t == 0) { *nrm = tots; *scl = sfac * totm / 127.0f; }
}

// ------------- main 256x256 reg-pipelined i8 MFMA GEMM --------------------
// LDS bytes: A[2buf][2half][128 rows][128 B] = 0..65535, B same 65536..131071.
__global__ __launch_bounds__(512, 2) void gemm_i8(
    const signed char* __restrict__ xq, const signed char* __restrict__ yq,
    const float* __restrict__ sx, const float* __restrict__ sy,
    const float* __restrict__ xsq, const float* __restrict__ ysq,
    float* __restrict__ out, int M, int N)
{
    __shared__ __align__(16) char lds[131072];   // 128 KiB

    const int ntm = M / BM;             // 16
    const int ntn = N / BN;             // 32
    const int bid = blockIdx.x;
    int tm, tn;
    if (ntm == 16 && ntn == 32) {
        int xcd = bid & 7, k = bid >> 3;            // 8x8-region XCD swizzle
        tm = (xcd >> 2) * 8 + (k >> 3);
        tn = (xcd & 3) * 8 + (k & 7);
    } else {
        tm = bid / ntn;
        tn = bid % ntn;
    }

    const int tid  = threadIdx.x;       // 512 threads = 8 waves
    const int wid  = tid >> 6;
    const int lane = tid & 63;
    const int wm   = wid >> 2;          // 0..1
    const int wn   = wid & 3;           // 0..3
    const int l15  = lane & 15;
    const int hi   = lane >> 4;         // 0..3
    const int s8   = lane & 7;

    // ---- staging (verified): dest LINEAR, global source 16B-block
    // pre-permuted: cbs = (lane&7) ^ ((lane>>3)&7). ----
    const int r8  = lane >> 3;
    const int cbs = s8 ^ (r8 & 7);
    const signed char* aBase = xq + (size_t)(tm * BM + wid * 16 + r8) * KD + cbs * 16;
    const signed char* bBase = yq + (size_t)(tn * BN + wid * 16 + r8) * KD + cbs * 16;
    const int dstBase = wid * 2048 + lane * 16;

    #define STAGE_A(kt, h) do {                                               \
        const signed char* g_ = aBase + (size_t)(h) * 128 * KD + (size_t)(kt) * 128; \
        char* d_ = &lds[((kt) & 1) * 32768 + (h) * 16384 + dstBase];          \
        gld16(g_, d_); gld16(g_ + 8 * KD, d_ + 1024);                         \
    } while (0)
    #define STAGE_B(kt, h) do {                                               \
        const signed char* g_ = bBase + (size_t)(h) * 128 * KD + (size_t)(kt) * 128; \
        char* d_ = &lds[65536 + ((kt) & 1) * 32768 + (h) * 16384 + dstBase];  \
        gld16(g_, d_); gld16(g_ + 8 * KD, d_ + 1024);                         \
    } while (0)

    // ---- fragment read offsets (bytes); phys 16B-block = (ks*4+hi) ^ s8 ----
    int aro[4], bro[2], xk[2];
    #pragma unroll
    for (int i = 0; i < 4; ++i) aro[i] = (wm * 64 + i * 16 + l15) * 128;
    #pragma unroll
    for (int j = 0; j < 2; ++j) bro[j] = (wn * 32 + j * 16 + l15) * 128;
    xk[0] = ((0 + hi) ^ s8) * 16;
    xk[1] = ((4 + hi) ^ s8) * 16;

    i32x4 acc[2][4][2][2] = {};     // [mq][i][nq][j]  64 regs
    i32x4 fA0[8], fB0[4];           // fragment set 0 (even steps' MFMA)
    i32x4 fA1[8], fB1[4];           // fragment set 1 (odd steps' MFMA)

    // read full-tile frags at k-half KS of tile base AB/BB into a set
    #define READS(FA, FB, AB, BB, KS) do {                                   \
        _Pragma("unroll") for (int h = 0; h < 2; ++h)                        \
        _Pragma("unroll") for (int i = 0; i < 4; ++i)                        \
            FA[h * 4 + i] = *(const i32x4*)&lds[(AB) + h * 16384 + aro[i] + xk[KS]]; \
        _Pragma("unroll") for (int h = 0; h < 2; ++h)                        \
        _Pragma("unroll") for (int j = 0; j < 2; ++j)                        \
            FB[h * 2 + j] = *(const i32x4*)&lds[(BB) + h * 16384 + bro[j] + xk[KS]]; \
    } while (0)

    #define MFMA_SET(FA, FB) do {                                            \
        __builtin_amdgcn_s_setprio(1);                                       \
        _Pragma("unroll") for (int mq = 0; mq < 2; ++mq)                     \
        _Pragma("unroll") for (int i = 0; i < 4; ++i)                        \
        _Pragma("unroll") for (int nq = 0; nq < 2; ++nq)                     \
        _Pragma("unroll") for (int j = 0; j < 2; ++j)                        \
            acc[mq][i][nq][j] = __builtin_amdgcn_mfma_i32_16x16x64_i8(       \
                FA[mq * 4 + i], FB[nq * 2 + j], acc[mq][i][nq][j], 0, 0, 0); \
        __builtin_amdgcn_s_setprio(0);                                       \
    } while (0)

    // ---- prologue: stage tile 0, drain, read frags(0, ks0) -> set0 ----
    STAGE_A(0, 0); STAGE_A(0, 1); STAGE_B(0, 0); STAGE_B(0, 1);
    asm volatile("s_waitcnt vmcnt(0)" ::: "memory");
    BAR();
    READS(fA0, fB0, 0, 65536, 0);

    #pragma unroll
    for (int k = 0; k < NT; ++k) {
        const int ab  = (k & 1) * 32768;
        const int bb  = 65536 + ab;
        const int abn = ((k + 1) & 1) * 32768;
        const int bbn = 65536 + abn;

        // ===== step (k,0): stage(k+1) || read frags(k,ks1)->set1 || MFMA set0
        if (k + 1 < NT) {
            STAGE_A(k + 1, 0); STAGE_A(k + 1, 1);
            STAGE_B(k + 1, 0); STAGE_B(k + 1, 1);
        }
        READS(fA1, fB1, ab, bb, 1);
        MFMA_SET(fA0, fB0);

        // ===== step (k,1): vmcnt(0)+BAR (cross-wave stage visibility);
        //        read frags(k+1,ks0)->set0 || MFMA set1
        if (k + 1 < NT) {
            asm volatile("s_waitcnt vmcnt(0)" ::: "memory");
            BAR();
            READS(fA0, fB0, abn, bbn, 0);
        }
        MFMA_SET(fA1, fB1);
    }

    // ---- epilogue: out = sx2[row]*sy[col]*dot - xsq[row] - ysq[col] ----
    // C/D layout (16x16): col = lane&15, row = (lane>>4)*4 + reg
    #pragma unroll
    for (int mq = 0; mq < 2; ++mq)
        #pragma unroll
        for (int i = 0; i < 4; ++i) {
            int r0 = tm * BM + mq * 128 + wm * 64 + i * 16 + hi * 4;
            #pragma unroll
            for (int nq = 0; nq < 2; ++nq)
                #pragma unroll
                for (int j = 0; j < 2; ++j) {
                    int c = tn * BN + nq * 128 + wn * 32 + j * 16 + l15;
                    float syv = sy[c];
                    float ysv = ysq[c];
                    #pragma unroll
                    for (int r = 0; r < 4; ++r) {
                        int row = r0 + r;
                        out[(size_t)row * N + c] =
                            sx[row] * syv * (float)acc[mq][i][nq][j][r]
                            - xsq[row] - ysv;
                    }
                }
        }
}

// ---------------- fallback (shape/ws mismatch): exact f32 -----------------
__global__ __launch_bounds__(256) void fallback_l2(
    const float* __restrict__ x, const float* __restrict__ y,
    float* __restrict__ out, int M, int N, int K)
{
    int tx = threadIdx.x & 15, ty = threadIdx.x >> 4;
    int row = blockIdx.y * 16 + ty;
    int col = blockIdx.x * 16 + tx;
    __shared__ float xs[16][17], ys[16][17];
    float s = 0.f;
    for (int k0 = 0; k0 < K; k0 += 16) {
        xs[ty][tx] = x[(size_t)row * K + k0 + tx];
        ys[ty][tx] = y[(size_t)(blockIdx.x * 16 + ty) * K + k0 + tx];
        __syncthreads();
        #pragma unroll
        for (int kk = 0; kk < 16; ++kk) {
            float d = xs[ty][kk] - ys[tx][kk];
            s += d * d;
        }
        __syncthreads();
    }
    out[(size_t)row * N + col] = -s;
}

extern "C" void kernel_launch(void* const* d_in, const int* in_sizes, int n_in,
                              void* d_out, int out_size, void* d_ws, size_t ws_size,
                              hipStream_t stream) {
    const float* x = (const float*)d_in[0];
    const float* y = (const float*)d_in[1];
    float* out = (float*)d_out;
    const int M = in_sizes[0] / KD;   // 4096
    const int N = in_sizes[1] / KD;   // 8192

    size_t need = (size_t)(M + N) * KD            // i8 matrices
                + (size_t)(M + N) * 2 * sizeof(float) + 256;
    if (ws_size >= need && M == 4096 && N == 8192) {
        char* w = (char*)d_ws;
        signed char* xq = (signed char*)w;
        signed char* yq = xq + (size_t)M * KD;
        float* sx  = (float*)(yq + (size_t)N * KD);
        float* sy  = sx + M;
        float* xsq = sy + N;
        float* ysq = xsq + M;

        prep_q<<<M + N, 256, 0, stream>>>(x, y, xq, yq, sx, sy, xsq, ysq, M, N);
        int grid = (M / BM) * (N / BN);   // 512
        gemm_i8<<<grid, 512, 0, stream>>>(xq, yq, sx, sy, xsq, ysq, out, M, N);
    } else {
        dim3 g(N / 16, M / 16);
        fallback_l2<<<g, 256, 0, stream>>>(x, y, out, M, N, KD);
    }
}